// Round 1
// baseline (499.926 us; speedup 1.0000x reference)
//
#include <hip/hip_runtime.h>
#include <hip/hip_bf16.h>
#include <math.h>

// GatedAttention pipeline, all-bf16 MFMA GEMMs (threshold 1.04e-1 is bf16-scale).
//
//  cast input -> cat[:, 0:1024] (bf16)            cast memory -> memory_bf16
//  transpose W_in1/W_mem1/W_in2 -> bf16 K-major   transpose memory -> memT
//  G1: input_dot = relu(cat[:, :1024] @ W1T^T + b1)          (M=16384,N=1024,K=1024)
//  G2: memory_dot = relu(memory_bf16 @ WmT^T + bm)           (M=4096, N=1024,K=1024)
//  G3: att = input_dot @ memory_dot^T / 32   [batched z=8]   (M=2048, N=512, K=1024)
//  softmax rows (mask) fp32 -> bf16 in place
//  G4: output_one = weight @ memT^T -> cat[:, 1024:2048]     (M=2048, N=1024,K=512)
//  G5: out = gate(cat @ W2T^T + b2)                          (M=16384,N=1024,K=2048)
//  copy memory fp32 -> out tail

using bf16_t = __hip_bfloat16;
typedef __attribute__((ext_vector_type(8))) __bf16 bf16x8;
typedef __attribute__((ext_vector_type(4))) float f32x4;

#define BM 128
#define BN 128
#define BK 32

#define EPI_RELU_BIAS_BF16 0
#define EPI_SCALE_F32      1
#define EPI_BF16           2
#define EPI_GATE_BIAS_F32  3

// C = A (M x K, row-major, lda) @ B^T (B is N x K row-major, ldb), batched via blockIdx.z.
template<int MODE>
__global__ __launch_bounds__(256)
void gemm_bt(const bf16_t* __restrict__ Ag, const bf16_t* __restrict__ Bg,
             void* __restrict__ Cg, const float* __restrict__ bias,
             int K, int lda, int ldb, int ldc,
             long sA, long sB, long sC, float scale)
{
    __shared__ alignas(16) bf16_t As[BM * BK];
    __shared__ alignas(16) bf16_t Bs[BN * BK];

    const int z = blockIdx.z;
    const bf16_t* A = Ag + (long)z * sA;
    const bf16_t* B = Bg + (long)z * sB;

    const int tid  = threadIdx.x;
    const int lane = tid & 63;
    const int wave = tid >> 6;
    const int wr   = (wave >> 1) * 64;   // wave row offset in 128x128 tile
    const int wc   = (wave & 1) * 64;    // wave col offset
    const int quad = lane >> 4;          // 0..3
    const int l16  = lane & 15;

    const long rowBase = (long)blockIdx.y * BM;
    const long colBase = (long)blockIdx.x * BN;

    f32x4 acc[4][4];
    #pragma unroll
    for (int i = 0; i < 4; ++i)
        #pragma unroll
        for (int j = 0; j < 4; ++j)
            acc[i][j] = (f32x4){0.f, 0.f, 0.f, 0.f};

    // staging: each thread loads 16B (8 bf16) twice per 128x32 tile
    const int e0  = tid * 8;
    const int r0s = e0 >> 5;   // row within tile (32 cols/row)
    const int c0s = e0 & 31;

    for (int k0 = 0; k0 < K; k0 += BK) {
        #pragma unroll
        for (int it = 0; it < 2; ++it) {
            const int r = r0s + it * 64;
            const uint4 va = *(const uint4*)(A + (rowBase + r) * lda + k0 + c0s);
            const uint4 vb = *(const uint4*)(B + (colBase + r) * ldb + k0 + c0s);
            *(uint4*)(&As[r * BK + c0s]) = va;
            *(uint4*)(&Bs[r * BK + c0s]) = vb;
        }
        __syncthreads();

        bf16x8 af[4], bfr[4];
        #pragma unroll
        for (int mi = 0; mi < 4; ++mi)
            af[mi] = *(const bf16x8*)(&As[(wr + mi * 16 + l16) * BK + quad * 8]);
        #pragma unroll
        for (int ni = 0; ni < 4; ++ni)
            bfr[ni] = *(const bf16x8*)(&Bs[(wc + ni * 16 + l16) * BK + quad * 8]);

        #pragma unroll
        for (int mi = 0; mi < 4; ++mi)
            #pragma unroll
            for (int ni = 0; ni < 4; ++ni)
                acc[mi][ni] = __builtin_amdgcn_mfma_f32_16x16x32_bf16(
                    af[mi], bfr[ni], acc[mi][ni], 0, 0, 0);
        __syncthreads();
    }

    // epilogue: C/D layout col = lane&15, row = quad*4 + reg
    #pragma unroll
    for (int mi = 0; mi < 4; ++mi) {
        #pragma unroll
        for (int ni = 0; ni < 4; ++ni) {
            #pragma unroll
            for (int r = 0; r < 4; ++r) {
                const long row = rowBase + wr + mi * 16 + quad * 4 + r;
                const long col = colBase + wc + ni * 16 + l16;
                const float v = acc[mi][ni][r];
                const long idx = (long)z * sC + row * ldc + col;
                if (MODE == EPI_RELU_BIAS_BF16) {
                    float t = v + bias[col];
                    t = t > 0.f ? t : 0.f;
                    ((bf16_t*)Cg)[idx] = __float2bfloat16(t);
                } else if (MODE == EPI_SCALE_F32) {
                    ((float*)Cg)[idx] = v * scale;
                } else if (MODE == EPI_BF16) {
                    ((bf16_t*)Cg)[idx] = __float2bfloat16(v);
                } else { // EPI_GATE_BIAS_F32
                    const float p  = v + bias[col];
                    const float sg = 1.0f / (1.0f + expf(-p));
                    const float th = tanhf(p);
                    ((float*)Cg)[idx] = sg * th;
                }
            }
        }
    }
}

// fp32 (rows of C elems, contiguous) -> bf16 with output leading dim ldo
__global__ void cast_f32_to_bf16(const float* __restrict__ in, bf16_t* __restrict__ out,
                                 long n, int shiftC, int ldo)
{
    const long total4 = n >> 2;
    const long stride = (long)gridDim.x * blockDim.x;
    const int  maskC  = (1 << shiftC) - 1;
    for (long i4 = blockIdx.x * (long)blockDim.x + threadIdx.x; i4 < total4; i4 += stride) {
        const long i = i4 << 2;
        const float4 v = ((const float4*)in)[i4];
        const long row = i >> shiftC;
        const int  col = (int)(i & maskC);
        bf16_t* o = out + row * (long)ldo + col;
        o[0] = __float2bfloat16(v.x);
        o[1] = __float2bfloat16(v.y);
        o[2] = __float2bfloat16(v.z);
        o[3] = __float2bfloat16(v.w);
    }
}

// out[c][r] = bf16(in[r][c]); in: R x C fp32, out: C x R bf16; batched via z
__global__ void transpose_f32_to_bf16(const float* __restrict__ in, bf16_t* __restrict__ out,
                                      int R, int C, long sIn, long sOut)
{
    __shared__ float tile[32][33];
    const int z = blockIdx.z;
    in  += (long)z * sIn;
    out += (long)z * sOut;
    const int c0 = blockIdx.x * 32;
    const int r0 = blockIdx.y * 32;
    const int x = threadIdx.x, y = threadIdx.y;
    #pragma unroll
    for (int i = 0; i < 32; i += 8)
        tile[y + i][x] = in[(long)(r0 + y + i) * C + c0 + x];
    __syncthreads();
    #pragma unroll
    for (int i = 0; i < 32; i += 8)
        out[(long)(c0 + y + i) * R + r0 + x] = __float2bfloat16(tile[x][y + i]);
}

// one wave per row of 512; att fp32 in, bf16 weights written in place (same bytes)
__global__ __launch_bounds__(256)
void softmax_rows(float* __restrict__ att, const int* __restrict__ mask)
{
    const int lane = threadIdx.x & 63;
    const long row = (long)blockIdx.x * 4 + (threadIdx.x >> 6);
    const int n = (int)(row >> 11);          // 2048 rows per batch
    float* base = att + row * 512;
    const int* mrow = mask + n * 512;

    float v[8];
    #pragma unroll
    for (int j = 0; j < 8; ++j) {
        const int idx = j * 64 + lane;
        const float x = base[idx];
        v[j] = mrow[idx] ? x : -1e30f;
    }
    float mx = v[0];
    #pragma unroll
    for (int j = 1; j < 8; ++j) mx = fmaxf(mx, v[j]);
    #pragma unroll
    for (int off = 32; off >= 1; off >>= 1) mx = fmaxf(mx, __shfl_xor(mx, off, 64));
    float s = 0.f;
    #pragma unroll
    for (int j = 0; j < 8; ++j) { v[j] = expf(v[j] - mx); s += v[j]; }
    #pragma unroll
    for (int off = 32; off >= 1; off >>= 1) s += __shfl_xor(s, off, 64);
    const float inv = 1.0f / s;

    bf16_t* w = (bf16_t*)base;  // same byte range; loads complete before stores (data dep)
    #pragma unroll
    for (int j = 0; j < 8; ++j)
        w[j * 64 + lane] = __float2bfloat16(v[j] * inv);
}

__global__ void copy_f32x4(const float4* __restrict__ in, float4* __restrict__ out, long n4)
{
    const long stride = (long)gridDim.x * blockDim.x;
    for (long i = blockIdx.x * (long)blockDim.x + threadIdx.x; i < n4; i += stride)
        out[i] = in[i];
}

extern "C" void kernel_launch(void* const* d_in, const int* in_sizes, int n_in,
                              void* d_out, int out_size, void* d_ws, size_t ws_size,
                              hipStream_t stream)
{
    const float* input  = (const float*)d_in[0];   // 8 x 2048 x 1024
    const float* memory = (const float*)d_in[1];   // 8 x 512 x 1024
    const int*   mask   = (const int*)  d_in[2];   // 8 x 512
    const float* W_in1  = (const float*)d_in[3];   // 1024 x 1024
    const float* b_in1  = (const float*)d_in[4];
    const float* W_mem1 = (const float*)d_in[5];   // 1024 x 1024
    const float* b_mem1 = (const float*)d_in[6];
    const float* W_in2  = (const float*)d_in[7];   // 2048 x 1024
    const float* b_in2  = (const float*)d_in[8];
    float* out = (float*)d_out;                    // 16777216 gated + 4194304 memory

    char* ws = (char*)d_ws;
    bf16_t* cat         = (bf16_t*)(ws);                 // 16384 x 2048   (67108864 B)
    bf16_t* input_dot   = (bf16_t*)(ws + 67108864);      // 16384 x 1024   (33554432 B)
    bf16_t* memory_dot  = (bf16_t*)(ws + 100663296);     //  4096 x 1024   ( 8388608 B)
    bf16_t* memory_bf16 = (bf16_t*)(ws + 109051904);     //  4096 x 1024   ( 8388608 B)
    bf16_t* memT        = (bf16_t*)(ws + 117440512);     // 8 x 1024 x 512 ( 8388608 B)
    bf16_t* W1T         = (bf16_t*)(ws + 125829120);     // 1024 x 1024    ( 2097152 B)
    bf16_t* WmT         = (bf16_t*)(ws + 127926272);     // 1024 x 1024    ( 2097152 B)
    bf16_t* W2T         = (bf16_t*)(ws + 130023424);     // 1024 x 2048    ( 4194304 B)
    float*  att         = (float*)(ws + 134217728);      // 8 x 2048 x 512 (33554432 B) -> end 167772160

    const dim3 tb(32, 8);

    // casts + transposes
    cast_f32_to_bf16<<<2048, 256, 0, stream>>>(input, cat, 16777216L, 10, 2048);
    cast_f32_to_bf16<<<1024, 256, 0, stream>>>(memory, memory_bf16, 4194304L, 10, 1024);
    transpose_f32_to_bf16<<<dim3(32, 32, 1), tb, 0, stream>>>(W_in1,  W1T, 1024, 1024, 0, 0);
    transpose_f32_to_bf16<<<dim3(32, 32, 1), tb, 0, stream>>>(W_mem1, WmT, 1024, 1024, 0, 0);
    transpose_f32_to_bf16<<<dim3(32, 64, 1), tb, 0, stream>>>(W_in2,  W2T, 2048, 1024, 0, 0);
    transpose_f32_to_bf16<<<dim3(32, 16, 8), tb, 0, stream>>>(memory, memT, 512, 1024,
                                                              524288L, 524288L);

    // G1: input_dot = relu(input @ W_in1 + b_in1)
    gemm_bt<EPI_RELU_BIAS_BF16><<<dim3(8, 128, 1), 256, 0, stream>>>(
        cat, W1T, input_dot, b_in1, 1024, 2048, 1024, 1024, 0, 0, 0, 1.0f);
    // G2: memory_dot = relu(memory @ W_mem1 + b_mem1)
    gemm_bt<EPI_RELU_BIAS_BF16><<<dim3(8, 32, 1), 256, 0, stream>>>(
        memory_bf16, WmT, memory_dot, b_mem1, 1024, 1024, 1024, 1024, 0, 0, 0, 1.0f);
    // G3: att = input_dot @ memory_dot^T / 32   (batched)
    gemm_bt<EPI_SCALE_F32><<<dim3(4, 16, 8), 256, 0, stream>>>(
        input_dot, memory_dot, att, nullptr, 1024, 1024, 1024, 512,
        2048L * 1024, 512L * 1024, 2048L * 512, 0.03125f);
    // softmax (in-place fp32 -> bf16)
    softmax_rows<<<4096, 256, 0, stream>>>(att, mask);
    // G4: output_one = weight @ memory -> cat[:, 1024:2048]   (batched)
    gemm_bt<EPI_BF16><<<dim3(8, 16, 8), 256, 0, stream>>>(
        (const bf16_t*)att, memT, cat + 1024, nullptr, 512, 1024, 512, 2048,
        2048L * 1024, 1024L * 512, 2048L * 2048, 1.0f);
    // G5: out = sigmoid(pre) * tanh(pre), pre = cat @ W_in2 + b_in2
    gemm_bt<EPI_GATE_BIAS_F32><<<dim3(8, 128, 1), 256, 0, stream>>>(
        cat, W2T, out, b_in2, 2048, 2048, 2048, 1024, 0, 0, 0, 1.0f);
    // memory passthrough -> out tail
    copy_f32x4<<<1024, 256, 0, stream>>>((const float4*)memory,
                                         (float4*)(out + 16777216L), 1048576L);
}

// Round 2
// 484.246 us; speedup vs baseline: 1.0324x; 1.0324x over previous
//
#include <hip/hip_runtime.h>
#include <hip/hip_bf16.h>
#include <math.h>

// GatedAttention pipeline, all-bf16 MFMA GEMMs (threshold 1.04e-1 is bf16-scale).
// R2: staging via __builtin_amdgcn_global_load_lds width=16 (m93->m97 ladder step).
//
//  cast input -> cat[:, 0:1024] (bf16)            cast memory -> memory_bf16
//  transpose W_in1/W_mem1/W_in2 -> bf16 K-major   transpose memory -> memT
//  G1: input_dot = relu(cat[:, :1024] @ W1T^T + b1)          (M=16384,N=1024,K=1024)
//  G2: memory_dot = relu(memory_bf16 @ WmT^T + bm)           (M=4096, N=1024,K=1024)
//  G3: att = input_dot @ memory_dot^T / 32   [batched z=8]   (M=2048, N=512, K=1024)
//  softmax rows (mask) fp32 -> bf16 in place
//  G4: output_one = weight @ memT^T -> cat[:, 1024:2048]     (M=2048, N=1024,K=512)
//  G5: out = gate(cat @ W2T^T + b2)                          (M=16384,N=1024,K=2048)
//  copy memory fp32 -> out tail

using bf16_t = __hip_bfloat16;
typedef __attribute__((ext_vector_type(8))) __bf16 bf16x8;
typedef __attribute__((ext_vector_type(4))) float f32x4;

#define BM 128
#define BN 128
#define BK 32

#define EPI_RELU_BIAS_BF16 0
#define EPI_SCALE_F32      1
#define EPI_BF16           2
#define EPI_GATE_BIAS_F32  3

// direct global->LDS DMA, 16B per lane; LDS dest = wave-uniform base + lane*16
#define GLD16(gp, lp)                                                        \
    __builtin_amdgcn_global_load_lds(                                        \
        (const __attribute__((address_space(1))) void*)(gp),                 \
        (__attribute__((address_space(3))) void*)(lp), 16, 0, 0)

// C = A (M x K, row-major, lda) @ B^T (B is N x K row-major, ldb), batched via blockIdx.z.
template<int MODE>
__global__ __launch_bounds__(256)
void gemm_bt(const bf16_t* __restrict__ Ag, const bf16_t* __restrict__ Bg,
             void* __restrict__ Cg, const float* __restrict__ bias,
             int K, int lda, int ldb, int ldc,
             long sA, long sB, long sC, float scale)
{
    __shared__ alignas(16) bf16_t As[BM * BK];
    __shared__ alignas(16) bf16_t Bs[BN * BK];

    const int z = blockIdx.z;
    const bf16_t* A = Ag + (long)z * sA;
    const bf16_t* B = Bg + (long)z * sB;

    const int tid  = threadIdx.x;
    const int lane = tid & 63;
    const int wave = tid >> 6;
    const int wr   = (wave >> 1) * 64;   // wave row offset in 128x128 tile
    const int wc   = (wave & 1) * 64;    // wave col offset
    const int quad = lane >> 4;          // 0..3
    const int l16  = lane & 15;

    const long rowBase = (long)blockIdx.y * BM;
    const long colBase = (long)blockIdx.x * BN;

    f32x4 acc[4][4];
    #pragma unroll
    for (int i = 0; i < 4; ++i)
        #pragma unroll
        for (int j = 0; j < 4; ++j)
            acc[i][j] = (f32x4){0.f, 0.f, 0.f, 0.f};

    // global_load_lds staging map: lane i of wave w, chunk `it`:
    //   LDS elem offset = (it*64 + w*16)*BK + i*8  -> row = it*64 + w*16 + (i>>2), col = (i&3)*8
    const int lrow = lane >> 2;          // 0..15
    const int lcol = (lane & 3) * 8;     // 0,8,16,24

    const bf16_t* gA0 = A + (rowBase + wave * 16 + lrow) * lda + lcol;
    const bf16_t* gB0 = B + (colBase + wave * 16 + lrow) * ldb + lcol;
    bf16_t* lA0 = &As[(wave * 16) * BK];
    bf16_t* lB0 = &Bs[(wave * 16) * BK];

    for (int k0 = 0; k0 < K; k0 += BK) {
        #pragma unroll
        for (int it = 0; it < 2; ++it) {
            GLD16(gA0 + (long)(it * 64) * lda + k0, lA0 + it * 64 * BK);
            GLD16(gB0 + (long)(it * 64) * ldb + k0, lB0 + it * 64 * BK);
        }
        __syncthreads();   // drains vmcnt (global_load_lds) + lgkmcnt

        bf16x8 af[4], bfr[4];
        #pragma unroll
        for (int mi = 0; mi < 4; ++mi)
            af[mi] = *(const bf16x8*)(&As[(wr + mi * 16 + l16) * BK + quad * 8]);
        #pragma unroll
        for (int ni = 0; ni < 4; ++ni)
            bfr[ni] = *(const bf16x8*)(&Bs[(wc + ni * 16 + l16) * BK + quad * 8]);

        #pragma unroll
        for (int mi = 0; mi < 4; ++mi)
            #pragma unroll
            for (int ni = 0; ni < 4; ++ni)
                acc[mi][ni] = __builtin_amdgcn_mfma_f32_16x16x32_bf16(
                    af[mi], bfr[ni], acc[mi][ni], 0, 0, 0);
        __syncthreads();
    }

    // epilogue: C/D layout col = lane&15, row = quad*4 + reg
    #pragma unroll
    for (int mi = 0; mi < 4; ++mi) {
        #pragma unroll
        for (int ni = 0; ni < 4; ++ni) {
            #pragma unroll
            for (int r = 0; r < 4; ++r) {
                const long row = rowBase + wr + mi * 16 + quad * 4 + r;
                const long col = colBase + wc + ni * 16 + l16;
                const float v = acc[mi][ni][r];
                const long idx = (long)z * sC + row * ldc + col;
                if (MODE == EPI_RELU_BIAS_BF16) {
                    float t = v + bias[col];
                    t = t > 0.f ? t : 0.f;
                    ((bf16_t*)Cg)[idx] = __float2bfloat16(t);
                } else if (MODE == EPI_SCALE_F32) {
                    ((float*)Cg)[idx] = v * scale;
                } else if (MODE == EPI_BF16) {
                    ((bf16_t*)Cg)[idx] = __float2bfloat16(v);
                } else { // EPI_GATE_BIAS_F32
                    const float p  = v + bias[col];
                    const float sg = 1.0f / (1.0f + expf(-p));
                    const float th = tanhf(p);
                    ((float*)Cg)[idx] = sg * th;
                }
            }
        }
    }
}

// fp32 (rows of C elems, contiguous) -> bf16 with output leading dim ldo
__global__ void cast_f32_to_bf16(const float* __restrict__ in, bf16_t* __restrict__ out,
                                 long n, int shiftC, int ldo)
{
    const long total4 = n >> 2;
    const long stride = (long)gridDim.x * blockDim.x;
    const int  maskC  = (1 << shiftC) - 1;
    for (long i4 = blockIdx.x * (long)blockDim.x + threadIdx.x; i4 < total4; i4 += stride) {
        const long i = i4 << 2;
        const float4 v = ((const float4*)in)[i4];
        const long row = i >> shiftC;
        const int  col = (int)(i & maskC);
        bf16_t* o = out + row * (long)ldo + col;
        o[0] = __float2bfloat16(v.x);
        o[1] = __float2bfloat16(v.y);
        o[2] = __float2bfloat16(v.z);
        o[3] = __float2bfloat16(v.w);
    }
}

// out[c][r] = bf16(in[r][c]); in: R x C fp32, out: C x R bf16; batched via z
__global__ void transpose_f32_to_bf16(const float* __restrict__ in, bf16_t* __restrict__ out,
                                      int R, int C, long sIn, long sOut)
{
    __shared__ float tile[32][33];
    const int z = blockIdx.z;
    in  += (long)z * sIn;
    out += (long)z * sOut;
    const int c0 = blockIdx.x * 32;
    const int r0 = blockIdx.y * 32;
    const int x = threadIdx.x, y = threadIdx.y;
    #pragma unroll
    for (int i = 0; i < 32; i += 8)
        tile[y + i][x] = in[(long)(r0 + y + i) * C + c0 + x];
    __syncthreads();
    #pragma unroll
    for (int i = 0; i < 32; i += 8)
        out[(long)(c0 + y + i) * R + r0 + x] = __float2bfloat16(tile[x][y + i]);
}

// one wave per row of 512; att fp32 in, bf16 weights written in place (same bytes)
__global__ __launch_bounds__(256)
void softmax_rows(float* __restrict__ att, const int* __restrict__ mask)
{
    const int lane = threadIdx.x & 63;
    const long row = (long)blockIdx.x * 4 + (threadIdx.x >> 6);
    const int n = (int)(row >> 11);          // 2048 rows per batch
    float* base = att + row * 512;
    const int* mrow = mask + n * 512;

    float v[8];
    #pragma unroll
    for (int j = 0; j < 8; ++j) {
        const int idx = j * 64 + lane;
        const float x = base[idx];
        v[j] = mrow[idx] ? x : -1e30f;
    }
    float mx = v[0];
    #pragma unroll
    for (int j = 1; j < 8; ++j) mx = fmaxf(mx, v[j]);
    #pragma unroll
    for (int off = 32; off >= 1; off >>= 1) mx = fmaxf(mx, __shfl_xor(mx, off, 64));
    float s = 0.f;
    #pragma unroll
    for (int j = 0; j < 8; ++j) { v[j] = expf(v[j] - mx); s += v[j]; }
    #pragma unroll
    for (int off = 32; off >= 1; off >>= 1) s += __shfl_xor(s, off, 64);
    const float inv = 1.0f / s;

    bf16_t* w = (bf16_t*)base;  // same byte range; loads complete before stores (data dep)
    #pragma unroll
    for (int j = 0; j < 8; ++j)
        w[j * 64 + lane] = __float2bfloat16(v[j] * inv);
}

__global__ void copy_f32x4(const float4* __restrict__ in, float4* __restrict__ out, long n4)
{
    const long stride = (long)gridDim.x * blockDim.x;
    for (long i = blockIdx.x * (long)blockDim.x + threadIdx.x; i < n4; i += stride)
        out[i] = in[i];
}

extern "C" void kernel_launch(void* const* d_in, const int* in_sizes, int n_in,
                              void* d_out, int out_size, void* d_ws, size_t ws_size,
                              hipStream_t stream)
{
    const float* input  = (const float*)d_in[0];   // 8 x 2048 x 1024
    const float* memory = (const float*)d_in[1];   // 8 x 512 x 1024
    const int*   mask   = (const int*)  d_in[2];   // 8 x 512
    const float* W_in1  = (const float*)d_in[3];   // 1024 x 1024
    const float* b_in1  = (const float*)d_in[4];
    const float* W_mem1 = (const float*)d_in[5];   // 1024 x 1024
    const float* b_mem1 = (const float*)d_in[6];
    const float* W_in2  = (const float*)d_in[7];   // 2048 x 1024
    const float* b_in2  = (const float*)d_in[8];
    float* out = (float*)d_out;                    // 16777216 gated + 4194304 memory

    char* ws = (char*)d_ws;
    bf16_t* cat         = (bf16_t*)(ws);                 // 16384 x 2048   (67108864 B)
    bf16_t* input_dot   = (bf16_t*)(ws + 67108864);      // 16384 x 1024   (33554432 B)
    bf16_t* memory_dot  = (bf16_t*)(ws + 100663296);     //  4096 x 1024   ( 8388608 B)
    bf16_t* memory_bf16 = (bf16_t*)(ws + 109051904);     //  4096 x 1024   ( 8388608 B)
    bf16_t* memT        = (bf16_t*)(ws + 117440512);     // 8 x 1024 x 512 ( 8388608 B)
    bf16_t* W1T         = (bf16_t*)(ws + 125829120);     // 1024 x 1024    ( 2097152 B)
    bf16_t* WmT         = (bf16_t*)(ws + 127926272);     // 1024 x 1024    ( 2097152 B)
    bf16_t* W2T         = (bf16_t*)(ws + 130023424);     // 1024 x 2048    ( 4194304 B)
    float*  att         = (float*)(ws + 134217728);      // 8 x 2048 x 512 (33554432 B) -> end 167772160

    const dim3 tb(32, 8);

    // casts + transposes
    cast_f32_to_bf16<<<2048, 256, 0, stream>>>(input, cat, 16777216L, 10, 2048);
    cast_f32_to_bf16<<<1024, 256, 0, stream>>>(memory, memory_bf16, 4194304L, 10, 1024);
    transpose_f32_to_bf16<<<dim3(32, 32, 1), tb, 0, stream>>>(W_in1,  W1T, 1024, 1024, 0, 0);
    transpose_f32_to_bf16<<<dim3(32, 32, 1), tb, 0, stream>>>(W_mem1, WmT, 1024, 1024, 0, 0);
    transpose_f32_to_bf16<<<dim3(32, 64, 1), tb, 0, stream>>>(W_in2,  W2T, 2048, 1024, 0, 0);
    transpose_f32_to_bf16<<<dim3(32, 16, 8), tb, 0, stream>>>(memory, memT, 512, 1024,
                                                              524288L, 524288L);

    // G1: input_dot = relu(input @ W_in1 + b_in1)
    gemm_bt<EPI_RELU_BIAS_BF16><<<dim3(8, 128, 1), 256, 0, stream>>>(
        cat, W1T, input_dot, b_in1, 1024, 2048, 1024, 1024, 0, 0, 0, 1.0f);
    // G2: memory_dot = relu(memory @ W_mem1 + b_mem1)
    gemm_bt<EPI_RELU_BIAS_BF16><<<dim3(8, 32, 1), 256, 0, stream>>>(
        memory_bf16, WmT, memory_dot, b_mem1, 1024, 1024, 1024, 1024, 0, 0, 0, 1.0f);
    // G3: att = input_dot @ memory_dot^T / 32   (batched)
    gemm_bt<EPI_SCALE_F32><<<dim3(4, 16, 8), 256, 0, stream>>>(
        input_dot, memory_dot, att, nullptr, 1024, 1024, 1024, 512,
        2048L * 1024, 512L * 1024, 2048L * 512, 0.03125f);
    // softmax (in-place fp32 -> bf16)
    softmax_rows<<<4096, 256, 0, stream>>>(att, mask);
    // G4: output_one = weight @ memory -> cat[:, 1024:2048]   (batched)
    gemm_bt<EPI_BF16><<<dim3(8, 16, 8), 256, 0, stream>>>(
        (const bf16_t*)att, memT, cat + 1024, nullptr, 512, 1024, 512, 2048,
        2048L * 1024, 1024L * 512, 2048L * 2048, 1.0f);
    // G5: out = sigmoid(pre) * tanh(pre), pre = cat @ W_in2 + b_in2
    gemm_bt<EPI_GATE_BIAS_F32><<<dim3(8, 128, 1), 256, 0, stream>>>(
        cat, W2T, out, b_in2, 2048, 2048, 2048, 1024, 0, 0, 0, 1.0f);
    // memory passthrough -> out tail
    copy_f32x4<<<1024, 256, 0, stream>>>((const float4*)memory,
                                         (float4*)(out + 16777216L), 1048576L);
}

// Round 4
// 466.666 us; speedup vs baseline: 1.0713x; 1.0377x over previous
//
#include <hip/hip_runtime.h>
#include <hip/hip_bf16.h>
#include <math.h>

// GatedAttention pipeline, all-bf16 MFMA GEMMs (threshold 1.04e-1 is bf16-scale).
// R4: R3 (compile-time dims, fast gate, fused prep) with G4 layout fix:
//     in-place softmax leaves bf16 rows at element stride 1024 (byte stride 2048),
//     so G4 must use LDA=1024, sA=2048*1024.  (R3 used 512 -> read garbage.)
//
//  prep: cast input -> cat[:, 0:1024], cast memory -> memory_bf16, copy memory -> out tail
//  transpose W_in1/W_mem1/W_in2 -> bf16 K-major   transpose memory -> memT
//  G1: input_dot = relu(cat[:, :1024] @ W1T^T + b1)          (M=16384,N=1024,K=1024)
//  G2: memory_dot = relu(memory_bf16 @ WmT^T + bm)           (M=4096, N=1024,K=1024)
//  G3: att = input_dot @ memory_dot^T / 32   [batched z=8]   (M=2048, N=512, K=1024)
//  softmax rows (mask) fp32 -> bf16 in place (bf16 row stride 1024 elems)
//  G4: output_one = weight @ memT^T -> cat[:, 1024:2048]     (M=2048, N=1024,K=512)
//  G5: out = gate(cat @ W2T^T + b2)                          (M=16384,N=1024,K=2048)

using bf16_t = __hip_bfloat16;
typedef __attribute__((ext_vector_type(8))) __bf16 bf16x8;
typedef __attribute__((ext_vector_type(4))) float f32x4;

#define BM 128
#define BN 128
#define BK 32

#define EPI_RELU_BIAS_BF16 0
#define EPI_SCALE_F32      1
#define EPI_BF16           2
#define EPI_GATE_BIAS_F32  3

// direct global->LDS DMA, 16B per lane; LDS dest = wave-uniform base + lane*16
#define GLD16(gp, lp)                                                        \
    __builtin_amdgcn_global_load_lds(                                        \
        (const __attribute__((address_space(1))) void*)(gp),                 \
        (__attribute__((address_space(3))) void*)(lp), 16, 0, 0)

// C = A (M x K, row-major, LDA) @ B^T (B is N x K row-major, LDB), batched via blockIdx.z.
// All dims compile-time so the K-loop address math folds to pointer increments.
template<int MODE, int K, int LDA, int LDB, int LDC>
__global__ __launch_bounds__(256)
void gemm_bt(const bf16_t* __restrict__ Ag, const bf16_t* __restrict__ Bg,
             void* __restrict__ Cg, const float* __restrict__ bias,
             long sA, long sB, long sC, float scale)
{
    __shared__ alignas(16) bf16_t As[BM * BK];
    __shared__ alignas(16) bf16_t Bs[BN * BK];

    const int z = blockIdx.z;
    const bf16_t* A = Ag + (long)z * sA;
    const bf16_t* B = Bg + (long)z * sB;

    const int tid  = threadIdx.x;
    const int lane = tid & 63;
    const int wave = tid >> 6;
    const int wr   = (wave >> 1) * 64;   // wave row offset in 128x128 tile
    const int wc   = (wave & 1) * 64;    // wave col offset
    const int quad = lane >> 4;          // 0..3
    const int l16  = lane & 15;

    const int rowBase = blockIdx.y * BM;
    const int colBase = blockIdx.x * BN;

    f32x4 acc[4][4];
    #pragma unroll
    for (int i = 0; i < 4; ++i)
        #pragma unroll
        for (int j = 0; j < 4; ++j)
            acc[i][j] = (f32x4){0.f, 0.f, 0.f, 0.f};

    // global_load_lds staging map: lane i of wave w, chunk `it`:
    //   LDS elem offset = (it*64 + w*16)*BK + i*8  -> row = it*64 + w*16 + (i>>2), col = (i&3)*8
    const int lrow = lane >> 2;          // 0..15
    const int lcol = (lane & 3) * 8;     // 0,8,16,24

    const bf16_t* pA0 = A + (long)(rowBase + wave * 16 + lrow) * LDA + lcol;
    const bf16_t* pA1 = pA0 + 64L * LDA;
    const bf16_t* pB0 = B + (long)(colBase + wave * 16 + lrow) * LDB + lcol;
    const bf16_t* pB1 = pB0 + 64L * LDB;
    bf16_t* lA0 = &As[(wave * 16) * BK];
    bf16_t* lA1 = lA0 + 64 * BK;
    bf16_t* lB0 = &Bs[(wave * 16) * BK];
    bf16_t* lB1 = lB0 + 64 * BK;

    #pragma unroll 1
    for (int k0 = 0; k0 < K; k0 += BK) {
        GLD16(pA0, lA0);
        GLD16(pA1, lA1);
        GLD16(pB0, lB0);
        GLD16(pB1, lB1);
        pA0 += BK; pA1 += BK; pB0 += BK; pB1 += BK;
        __syncthreads();   // drains vmcnt (global_load_lds) + lgkmcnt

        bf16x8 af[4], bfr[4];
        #pragma unroll
        for (int mi = 0; mi < 4; ++mi)
            af[mi] = *(const bf16x8*)(&As[(wr + mi * 16 + l16) * BK + quad * 8]);
        #pragma unroll
        for (int ni = 0; ni < 4; ++ni)
            bfr[ni] = *(const bf16x8*)(&Bs[(wc + ni * 16 + l16) * BK + quad * 8]);

        #pragma unroll
        for (int mi = 0; mi < 4; ++mi)
            #pragma unroll
            for (int ni = 0; ni < 4; ++ni)
                acc[mi][ni] = __builtin_amdgcn_mfma_f32_16x16x32_bf16(
                    af[mi], bfr[ni], acc[mi][ni], 0, 0, 0);
        __syncthreads();
    }

    // epilogue: C/D layout col = lane&15, row = quad*4 + reg
    #pragma unroll
    for (int mi = 0; mi < 4; ++mi) {
        #pragma unroll
        for (int ni = 0; ni < 4; ++ni) {
            #pragma unroll
            for (int r = 0; r < 4; ++r) {
                const int row = rowBase + wr + mi * 16 + quad * 4 + r;
                const int col = colBase + wc + ni * 16 + l16;
                const float v = acc[mi][ni][r];
                const long idx = (long)z * sC + (long)row * LDC + col;
                if (MODE == EPI_RELU_BIAS_BF16) {
                    float t = v + bias[col];
                    t = t > 0.f ? t : 0.f;
                    ((bf16_t*)Cg)[idx] = __float2bfloat16(t);
                } else if (MODE == EPI_SCALE_F32) {
                    ((float*)Cg)[idx] = v * scale;
                } else if (MODE == EPI_BF16) {
                    ((bf16_t*)Cg)[idx] = __float2bfloat16(v);
                } else { // EPI_GATE_BIAS_F32: sigmoid(p)*tanh(p) via one exp
                    float p = v + bias[col];
                    p = fminf(fmaxf(p, -30.f), 30.f);
                    const float u  = __expf(-p);
                    const float u2 = u * u;
                    ((float*)Cg)[idx] = (1.f - u2) / ((1.f + u) * (1.f + u2));
                }
            }
        }
    }
}

// fused prep: cast input (16M f32) -> cat[:, :1024] bf16 (ldo 2048),
//             cast memory (4M f32) -> memory_bf16 (contig),
//             copy memory (4M f32) -> out tail.
// grid covers 6291456 float4 groups exactly.
__global__ __launch_bounds__(256)
void prep(const float4* __restrict__ input, const float4* __restrict__ memory,
          bf16_t* __restrict__ cat, bf16_t* __restrict__ memb,
          float4* __restrict__ outTail)
{
    const long i = (long)blockIdx.x * blockDim.x + threadIdx.x;
    if (i < 4194304L) {               // input cast -> cat left half
        const float4 v = input[i];
        const long e = i << 2;
        const long row = e >> 10;
        const int  col = (int)(e & 1023);
        bf16_t* o = cat + row * 2048 + col;
        o[0] = __float2bfloat16(v.x);
        o[1] = __float2bfloat16(v.y);
        o[2] = __float2bfloat16(v.z);
        o[3] = __float2bfloat16(v.w);
    } else if (i < 5242880L) {        // memory cast (contiguous)
        const long j = i - 4194304L;
        const float4 v = memory[j];
        bf16_t* o = memb + (j << 2);
        o[0] = __float2bfloat16(v.x);
        o[1] = __float2bfloat16(v.y);
        o[2] = __float2bfloat16(v.z);
        o[3] = __float2bfloat16(v.w);
    } else {                          // memory passthrough -> out tail
        const long j = i - 5242880L;
        outTail[j] = memory[j];
    }
}

// out[c][r] = bf16(in[r][c]); in: R x C fp32, out: C x R bf16; batched via z
__global__ void transpose_f32_to_bf16(const float* __restrict__ in, bf16_t* __restrict__ out,
                                      int R, int C, long sIn, long sOut)
{
    __shared__ float tile[32][33];
    const int z = blockIdx.z;
    in  += (long)z * sIn;
    out += (long)z * sOut;
    const int c0 = blockIdx.x * 32;
    const int r0 = blockIdx.y * 32;
    const int x = threadIdx.x, y = threadIdx.y;
    #pragma unroll
    for (int i = 0; i < 32; i += 8)
        tile[y + i][x] = in[(long)(r0 + y + i) * C + c0 + x];
    __syncthreads();
    #pragma unroll
    for (int i = 0; i < 32; i += 8)
        out[(long)(c0 + y + i) * R + r0 + x] = __float2bfloat16(tile[x][y + i]);
}

// one wave per row of 512; att fp32 in, bf16 weights written in place (same bytes).
// NOTE: resulting bf16 rows live at ELEMENT stride 1024 (byte stride 2048).
__global__ __launch_bounds__(256)
void softmax_rows(float* __restrict__ att, const int* __restrict__ mask)
{
    const int lane = threadIdx.x & 63;
    const long row = (long)blockIdx.x * 4 + (threadIdx.x >> 6);
    const int n = (int)(row >> 11);          // 2048 rows per batch
    float* base = att + row * 512;
    const int* mrow = mask + n * 512;

    float v[8];
    #pragma unroll
    for (int j = 0; j < 8; ++j) {
        const int idx = j * 64 + lane;
        const float x = base[idx];
        v[j] = mrow[idx] ? x : -1e30f;
    }
    float mx = v[0];
    #pragma unroll
    for (int j = 1; j < 8; ++j) mx = fmaxf(mx, v[j]);
    #pragma unroll
    for (int off = 32; off >= 1; off >>= 1) mx = fmaxf(mx, __shfl_xor(mx, off, 64));
    float s = 0.f;
    #pragma unroll
    for (int j = 0; j < 8; ++j) { v[j] = __expf(v[j] - mx); s += v[j]; }
    #pragma unroll
    for (int off = 32; off >= 1; off >>= 1) s += __shfl_xor(s, off, 64);
    const float inv = 1.0f / s;

    bf16_t* w = (bf16_t*)base;  // same byte range; loads complete before stores (data dep)
    #pragma unroll
    for (int j = 0; j < 8; ++j)
        w[j * 64 + lane] = __float2bfloat16(v[j] * inv);
}

extern "C" void kernel_launch(void* const* d_in, const int* in_sizes, int n_in,
                              void* d_out, int out_size, void* d_ws, size_t ws_size,
                              hipStream_t stream)
{
    const float* input  = (const float*)d_in[0];   // 8 x 2048 x 1024
    const float* memory = (const float*)d_in[1];   // 8 x 512 x 1024
    const int*   mask   = (const int*)  d_in[2];   // 8 x 512
    const float* W_in1  = (const float*)d_in[3];   // 1024 x 1024
    const float* b_in1  = (const float*)d_in[4];
    const float* W_mem1 = (const float*)d_in[5];   // 1024 x 1024
    const float* b_mem1 = (const float*)d_in[6];
    const float* W_in2  = (const float*)d_in[7];   // 2048 x 1024
    const float* b_in2  = (const float*)d_in[8];
    float* out = (float*)d_out;                    // 16777216 gated + 4194304 memory

    char* ws = (char*)d_ws;
    bf16_t* cat         = (bf16_t*)(ws);                 // 16384 x 2048   (67108864 B)
    bf16_t* input_dot   = (bf16_t*)(ws + 67108864);      // 16384 x 1024   (33554432 B)
    bf16_t* memory_dot  = (bf16_t*)(ws + 100663296);     //  4096 x 1024   ( 8388608 B)
    bf16_t* memory_bf16 = (bf16_t*)(ws + 109051904);     //  4096 x 1024   ( 8388608 B)
    bf16_t* memT        = (bf16_t*)(ws + 117440512);     // 8 x 1024 x 512 ( 8388608 B)
    bf16_t* W1T         = (bf16_t*)(ws + 125829120);     // 1024 x 1024    ( 2097152 B)
    bf16_t* WmT         = (bf16_t*)(ws + 127926272);     // 1024 x 1024    ( 2097152 B)
    bf16_t* W2T         = (bf16_t*)(ws + 130023424);     // 1024 x 2048    ( 4194304 B)
    float*  att         = (float*)(ws + 134217728);      // 8 x 2048 x 512 (33554432 B) -> end 167772160

    const dim3 tb(32, 8);

    // prep (casts + passthrough copy) + weight/memory transposes
    prep<<<24576, 256, 0, stream>>>((const float4*)input, (const float4*)memory,
                                    cat, memory_bf16, (float4*)(out + 16777216L));
    transpose_f32_to_bf16<<<dim3(32, 32, 1), tb, 0, stream>>>(W_in1,  W1T, 1024, 1024, 0, 0);
    transpose_f32_to_bf16<<<dim3(32, 32, 1), tb, 0, stream>>>(W_mem1, WmT, 1024, 1024, 0, 0);
    transpose_f32_to_bf16<<<dim3(32, 64, 1), tb, 0, stream>>>(W_in2,  W2T, 2048, 1024, 0, 0);
    transpose_f32_to_bf16<<<dim3(32, 16, 8), tb, 0, stream>>>(memory, memT, 512, 1024,
                                                              524288L, 524288L);

    // G1: input_dot = relu(input @ W_in1 + b_in1)
    gemm_bt<EPI_RELU_BIAS_BF16, 1024, 2048, 1024, 1024><<<dim3(8, 128, 1), 256, 0, stream>>>(
        cat, W1T, input_dot, b_in1, 0, 0, 0, 1.0f);
    // G2: memory_dot = relu(memory @ W_mem1 + b_mem1)
    gemm_bt<EPI_RELU_BIAS_BF16, 1024, 1024, 1024, 1024><<<dim3(8, 32, 1), 256, 0, stream>>>(
        memory_bf16, WmT, memory_dot, b_mem1, 0, 0, 0, 1.0f);
    // G3: att = input_dot @ memory_dot^T / 32   (batched)
    gemm_bt<EPI_SCALE_F32, 1024, 1024, 1024, 512><<<dim3(4, 16, 8), 256, 0, stream>>>(
        input_dot, memory_dot, att, nullptr,
        2048L * 1024, 512L * 1024, 2048L * 512, 0.03125f);
    // softmax (in-place fp32 -> bf16; bf16 rows at elem stride 1024)
    softmax_rows<<<4096, 256, 0, stream>>>(att, mask);
    // G4: output_one = weight @ memory -> cat[:, 1024:2048]   (batched)
    //     LDA=1024 because softmax's in-place bf16 rows sit at elem stride 1024.
    gemm_bt<EPI_BF16, 512, 1024, 512, 2048><<<dim3(8, 16, 8), 256, 0, stream>>>(
        (const bf16_t*)att, memT, cat + 1024, nullptr,
        2048L * 1024, 1024L * 512, 2048L * 2048, 1.0f);
    // G5: out = sigmoid(pre) * tanh(pre), pre = cat @ W_in2 + b_in2
    gemm_bt<EPI_GATE_BIAS_F32, 2048, 2048, 2048, 1024><<<dim3(8, 128, 1), 256, 0, stream>>>(
        cat, W2T, out, b_in2, 0, 0, 0, 1.0f);
}

// Round 5
// 445.119 us; speedup vs baseline: 1.1231x; 1.0484x over previous
//
#include <hip/hip_runtime.h>
#include <hip/hip_bf16.h>
#include <math.h>

// GatedAttention pipeline, all-bf16 MFMA GEMMs (threshold 1.04e-1 is bf16-scale).
// R5: (1) XCD-aware block remap in gemm_bt (column-major linear ID) so the
//     blocks sharing an A row-tile land on ONE XCD's L2 -> kill the 4x A
//     over-fetch seen in FETCH_SIZE (266 MB vs ~71 ideal on G5).
//     (2) softmax writes compact bf16 weights into the dead input_dot buffer
//     (G4 reads dense, LDA=512).  (3) prep + 4 transposes fused -> 6 dispatches.
//
//  prep_all: cast input -> cat[:, :1024]; cast memory -> memory_bf16;
//            copy memory -> out tail; transpose W_in1/W_mem1/W_in2/memory
//  G1: input_dot = relu(cat[:, :1024] @ W1T^T + b1)          (M=16384,N=1024,K=1024)
//  G2: memory_dot = relu(memory_bf16 @ WmT^T + bm)           (M=4096, N=1024,K=1024)
//  G3: att = input_dot @ memory_dot^T / 32   [batched z=8]   (M=2048, N=512, K=1024)
//  softmax rows (mask) fp32 att -> compact bf16 wAtt (=input_dot buffer)
//  G4: output_one = wAtt @ memT^T -> cat[:, 1024:2048]       (M=2048, N=1024,K=512)
//  G5: out = gate(cat @ W2T^T + b2)                          (M=16384,N=1024,K=2048)

using bf16_t = __hip_bfloat16;
typedef __attribute__((ext_vector_type(8))) __bf16 bf16x8;
typedef __attribute__((ext_vector_type(4))) float f32x4;

#define BM 128
#define BN 128
#define BK 32

#define EPI_RELU_BIAS_BF16 0
#define EPI_SCALE_F32      1
#define EPI_BF16           2
#define EPI_GATE_BIAS_F32  3

// direct global->LDS DMA, 16B per lane; LDS dest = wave-uniform base + lane*16
#define GLD16(gp, lp)                                                        \
    __builtin_amdgcn_global_load_lds(                                        \
        (const __attribute__((address_space(1))) void*)(gp),                 \
        (__attribute__((address_space(3))) void*)(lp), 16, 0, 0)

// C = A (M x K, row-major, LDA) @ B^T (B is N x K row-major, LDB), batched via blockIdx.z.
// Compile-time dims; XCD-aware block remap: linear ID interpreted column-major so
// all blocks sharing a row-tile have lin % 8 == rowBlk % 8 (gridDim.y % 8 == 0)
// -> same XCD -> A row-tile fetched once into that XCD's L2.
template<int MODE, int K, int LDA, int LDB, int LDC>
__global__ __launch_bounds__(256)
void gemm_bt(const bf16_t* __restrict__ Ag, const bf16_t* __restrict__ Bg,
             void* __restrict__ Cg, const float* __restrict__ bias,
             long sA, long sB, long sC, float scale)
{
    __shared__ alignas(16) bf16_t As[BM * BK];
    __shared__ alignas(16) bf16_t Bs[BN * BK];

    const int z = blockIdx.z;
    const bf16_t* A = Ag + (long)z * sA;
    const bf16_t* B = Bg + (long)z * sB;

    const int tid  = threadIdx.x;
    const int lane = tid & 63;
    const int wave = tid >> 6;
    const int wr   = (wave >> 1) * 64;   // wave row offset in 128x128 tile
    const int wc   = (wave & 1) * 64;    // wave col offset
    const int quad = lane >> 4;          // 0..3
    const int l16  = lane & 15;

    // XCD swizzle: column-major reinterpretation of the linear block ID
    const int bidLin = blockIdx.y * gridDim.x + blockIdx.x;
    const int colBlk = bidLin / gridDim.y;
    const int rowBlk = bidLin - colBlk * gridDim.y;
    const int rowBase = rowBlk * BM;
    const int colBase = colBlk * BN;

    f32x4 acc[4][4];
    #pragma unroll
    for (int i = 0; i < 4; ++i)
        #pragma unroll
        for (int j = 0; j < 4; ++j)
            acc[i][j] = (f32x4){0.f, 0.f, 0.f, 0.f};

    // global_load_lds staging map: lane i of wave w, chunk `it`:
    //   LDS elem offset = (it*64 + w*16)*BK + i*8  -> row = it*64 + w*16 + (i>>2), col = (i&3)*8
    const int lrow = lane >> 2;          // 0..15
    const int lcol = (lane & 3) * 8;     // 0,8,16,24

    const bf16_t* pA0 = A + (long)(rowBase + wave * 16 + lrow) * LDA + lcol;
    const bf16_t* pA1 = pA0 + 64L * LDA;
    const bf16_t* pB0 = B + (long)(colBase + wave * 16 + lrow) * LDB + lcol;
    const bf16_t* pB1 = pB0 + 64L * LDB;
    bf16_t* lA0 = &As[(wave * 16) * BK];
    bf16_t* lA1 = lA0 + 64 * BK;
    bf16_t* lB0 = &Bs[(wave * 16) * BK];
    bf16_t* lB1 = lB0 + 64 * BK;

    #pragma unroll 1
    for (int k0 = 0; k0 < K; k0 += BK) {
        GLD16(pA0, lA0);
        GLD16(pA1, lA1);
        GLD16(pB0, lB0);
        GLD16(pB1, lB1);
        pA0 += BK; pA1 += BK; pB0 += BK; pB1 += BK;
        __syncthreads();   // drains vmcnt (global_load_lds) + lgkmcnt

        bf16x8 af[4], bfr[4];
        #pragma unroll
        for (int mi = 0; mi < 4; ++mi)
            af[mi] = *(const bf16x8*)(&As[(wr + mi * 16 + l16) * BK + quad * 8]);
        #pragma unroll
        for (int ni = 0; ni < 4; ++ni)
            bfr[ni] = *(const bf16x8*)(&Bs[(wc + ni * 16 + l16) * BK + quad * 8]);

        #pragma unroll
        for (int mi = 0; mi < 4; ++mi)
            #pragma unroll
            for (int ni = 0; ni < 4; ++ni)
                acc[mi][ni] = __builtin_amdgcn_mfma_f32_16x16x32_bf16(
                    af[mi], bfr[ni], acc[mi][ni], 0, 0, 0);
        __syncthreads();
    }

    // epilogue: C/D layout col = lane&15, row = quad*4 + reg
    #pragma unroll
    for (int mi = 0; mi < 4; ++mi) {
        #pragma unroll
        for (int ni = 0; ni < 4; ++ni) {
            #pragma unroll
            for (int r = 0; r < 4; ++r) {
                const int row = rowBase + wr + mi * 16 + quad * 4 + r;
                const int col = colBase + wc + ni * 16 + l16;
                const float v = acc[mi][ni][r];
                const long idx = (long)z * sC + (long)row * LDC + col;
                if (MODE == EPI_RELU_BIAS_BF16) {
                    float t = v + bias[col];
                    t = t > 0.f ? t : 0.f;
                    ((bf16_t*)Cg)[idx] = __float2bfloat16(t);
                } else if (MODE == EPI_SCALE_F32) {
                    ((float*)Cg)[idx] = v * scale;
                } else if (MODE == EPI_BF16) {
                    ((bf16_t*)Cg)[idx] = __float2bfloat16(v);
                } else { // EPI_GATE_BIAS_F32: sigmoid(p)*tanh(p) via one exp
                    float p = v + bias[col];
                    p = fminf(fmaxf(p, -30.f), 30.f);
                    const float u  = __expf(-p);
                    const float u2 = u * u;
                    ((float*)Cg)[idx] = (1.f - u2) / ((1.f + u) * (1.f + u2));
                }
            }
        }
    }
}

// fused prep: blocks [0,24576): cast input -> cat left half, cast memory -> memb,
//             copy memory -> out tail (float4 groups).
//             blocks [24576,32768): 32x32 transpose tiles for W1T/WmT/W2T/memT.
__global__ __launch_bounds__(256)
void prep_all(const float4* __restrict__ input, const float4* __restrict__ memory,
              const float* __restrict__ W_in1, const float* __restrict__ W_mem1,
              const float* __restrict__ W_in2,
              bf16_t* __restrict__ cat, bf16_t* __restrict__ memb,
              float4* __restrict__ outTail,
              bf16_t* __restrict__ W1T, bf16_t* __restrict__ WmT,
              bf16_t* __restrict__ W2T, bf16_t* __restrict__ memT)
{
    __shared__ float tile[32][33];
    const int bid = blockIdx.x;
    if (bid < 24576) {
        const long i = (long)bid * 256 + threadIdx.x;
        if (i < 4194304L) {               // input cast -> cat left half
            const float4 v = input[i];
            const long e = i << 2;
            const long row = e >> 10;
            const int  col = (int)(e & 1023);
            bf16_t* o = cat + row * 2048 + col;
            o[0] = __float2bfloat16(v.x);
            o[1] = __float2bfloat16(v.y);
            o[2] = __float2bfloat16(v.z);
            o[3] = __float2bfloat16(v.w);
        } else if (i < 5242880L) {        // memory cast (contiguous)
            const long j = i - 4194304L;
            const float4 v = memory[j];
            bf16_t* o = memb + (j << 2);
            o[0] = __float2bfloat16(v.x);
            o[1] = __float2bfloat16(v.y);
            o[2] = __float2bfloat16(v.z);
            o[3] = __float2bfloat16(v.w);
        } else {                          // memory passthrough -> out tail
            const long j = i - 5242880L;
            outTail[j] = memory[j];
        }
        return;
    }

    // transpose section: out[c][r] = bf16(in[r][c]), 32x32 tiles
    int local = bid - 24576;
    const float* in; bf16_t* out; int R, C, bx, by;
    if (local < 1024)      { in = W_in1;  out = W1T; R = 1024; C = 1024;
                             bx = local & 31; by = local >> 5; }
    else if (local < 2048) { local -= 1024; in = W_mem1; out = WmT; R = 1024; C = 1024;
                             bx = local & 31; by = local >> 5; }
    else if (local < 4096) { local -= 2048; in = W_in2;  out = W2T; R = 2048; C = 1024;
                             bx = local & 31; by = local >> 5; }
    else                   { local -= 4096;
                             const int zz = local >> 9;          // 0..7
                             const int r  = local & 511;
                             bx = r & 31; by = r >> 5;           // by 0..15
                             in  = (const float*)memory + (long)zz * 524288;
                             out = memT + (long)zz * 524288;
                             R = 512; C = 1024; }

    const int x = threadIdx.x & 31, y = threadIdx.x >> 5;   // y in 0..7
    const int c0 = bx * 32, r0 = by * 32;
    #pragma unroll
    for (int i = 0; i < 32; i += 8)
        tile[y + i][x] = in[(long)(r0 + y + i) * C + c0 + x];
    __syncthreads();
    #pragma unroll
    for (int i = 0; i < 32; i += 8)
        out[(long)(c0 + y + i) * R + r0 + x] = __float2bfloat16(tile[x][y + i]);
}

// one wave per row of 512; att fp32 in, compact bf16 weights out (row stride 512).
__global__ __launch_bounds__(256)
void softmax_rows(const float* __restrict__ att, const int* __restrict__ mask,
                  bf16_t* __restrict__ wAtt)
{
    const int lane = threadIdx.x & 63;
    const long row = (long)blockIdx.x * 4 + (threadIdx.x >> 6);
    const int n = (int)(row >> 11);          // 2048 rows per batch
    const float* base = att + row * 512;
    const int* mrow = mask + n * 512;

    float v[8];
    #pragma unroll
    for (int j = 0; j < 8; ++j) {
        const int idx = j * 64 + lane;
        const float x = base[idx];
        v[j] = mrow[idx] ? x : -1e30f;
    }
    float mx = v[0];
    #pragma unroll
    for (int j = 1; j < 8; ++j) mx = fmaxf(mx, v[j]);
    #pragma unroll
    for (int off = 32; off >= 1; off >>= 1) mx = fmaxf(mx, __shfl_xor(mx, off, 64));
    float s = 0.f;
    #pragma unroll
    for (int j = 0; j < 8; ++j) { v[j] = __expf(v[j] - mx); s += v[j]; }
    #pragma unroll
    for (int off = 32; off >= 1; off >>= 1) s += __shfl_xor(s, off, 64);
    const float inv = 1.0f / s;

    bf16_t* w = wAtt + row * 512;
    #pragma unroll
    for (int j = 0; j < 8; ++j)
        w[j * 64 + lane] = __float2bfloat16(v[j] * inv);
}

extern "C" void kernel_launch(void* const* d_in, const int* in_sizes, int n_in,
                              void* d_out, int out_size, void* d_ws, size_t ws_size,
                              hipStream_t stream)
{
    const float* input  = (const float*)d_in[0];   // 8 x 2048 x 1024
    const float* memory = (const float*)d_in[1];   // 8 x 512 x 1024
    const int*   mask   = (const int*)  d_in[2];   // 8 x 512
    const float* W_in1  = (const float*)d_in[3];   // 1024 x 1024
    const float* b_in1  = (const float*)d_in[4];
    const float* W_mem1 = (const float*)d_in[5];   // 1024 x 1024
    const float* b_mem1 = (const float*)d_in[6];
    const float* W_in2  = (const float*)d_in[7];   // 2048 x 1024
    const float* b_in2  = (const float*)d_in[8];
    float* out = (float*)d_out;                    // 16777216 gated + 4194304 memory

    char* ws = (char*)d_ws;
    bf16_t* cat         = (bf16_t*)(ws);                 // 16384 x 2048   (67108864 B)
    bf16_t* input_dot   = (bf16_t*)(ws + 67108864);      // 16384 x 1024   (33554432 B)
    bf16_t* memory_dot  = (bf16_t*)(ws + 100663296);     //  4096 x 1024   ( 8388608 B)
    bf16_t* memory_bf16 = (bf16_t*)(ws + 109051904);     //  4096 x 1024   ( 8388608 B)
    bf16_t* memT        = (bf16_t*)(ws + 117440512);     // 8 x 1024 x 512 ( 8388608 B)
    bf16_t* W1T         = (bf16_t*)(ws + 125829120);     // 1024 x 1024    ( 2097152 B)
    bf16_t* WmT         = (bf16_t*)(ws + 127926272);     // 1024 x 1024    ( 2097152 B)
    bf16_t* W2T         = (bf16_t*)(ws + 130023424);     // 1024 x 2048    ( 4194304 B)
    float*  att         = (float*)(ws + 134217728);      // 8 x 2048 x 512 (33554432 B) -> end 167772160
    bf16_t* wAtt        = input_dot;   // reclaimed after G3: compact bf16 softmax weights

    // fused prep (casts + passthrough + all transposes)
    prep_all<<<32768, 256, 0, stream>>>((const float4*)input, (const float4*)memory,
                                        W_in1, W_mem1, W_in2,
                                        cat, memory_bf16, (float4*)(out + 16777216L),
                                        W1T, WmT, W2T, memT);

    // G1: input_dot = relu(input @ W_in1 + b_in1)
    gemm_bt<EPI_RELU_BIAS_BF16, 1024, 2048, 1024, 1024><<<dim3(8, 128, 1), 256, 0, stream>>>(
        cat, W1T, input_dot, b_in1, 0, 0, 0, 1.0f);
    // G2: memory_dot = relu(memory @ W_mem1 + b_mem1)
    gemm_bt<EPI_RELU_BIAS_BF16, 1024, 1024, 1024, 1024><<<dim3(8, 32, 1), 256, 0, stream>>>(
        memory_bf16, WmT, memory_dot, b_mem1, 0, 0, 0, 1.0f);
    // G3: att = input_dot @ memory_dot^T / 32   (batched)
    gemm_bt<EPI_SCALE_F32, 1024, 1024, 1024, 512><<<dim3(4, 16, 8), 256, 0, stream>>>(
        input_dot, memory_dot, att, nullptr,
        2048L * 1024, 512L * 1024, 2048L * 512, 0.03125f);
    // softmax: fp32 att -> compact bf16 wAtt (input_dot buffer is dead after G3)
    softmax_rows<<<4096, 256, 0, stream>>>(att, mask, wAtt);
    // G4: output_one = wAtt @ memT^T -> cat[:, 1024:2048]   (batched, dense A)
    gemm_bt<EPI_BF16, 512, 512, 512, 2048><<<dim3(8, 16, 8), 256, 0, stream>>>(
        wAtt, memT, cat + 1024, nullptr,
        2048L * 512, 1024L * 512, 2048L * 2048, 1.0f);
    // G5: out = sigmoid(pre) * tanh(pre), pre = cat @ W_in2 + b_in2
    gemm_bt<EPI_GATE_BIAS_F32, 2048, 2048, 2048, 1024><<<dim3(8, 128, 1), 256, 0, stream>>>(
        cat, W2T, out, b_in2, 0, 0, 0, 1.0f);
}

// Round 6
// 387.251 us; speedup vs baseline: 1.2910x; 1.1494x over previous
//
#include <hip/hip_runtime.h>
#include <hip/hip_bf16.h>
#include <math.h>

// GatedAttention pipeline, all-bf16 MFMA GEMMs (threshold 1.04e-1 is bf16-scale).
// R6: BK=64 (half the barriers, 32KB LDS) + XOR chunk swizzle so ds_read_b128
//     fragment reads are bank-conflict-free (R5 counter showed constant 8.4M
//     conflicts = 8-way aliasing from the row*64B + quad*16B pattern).
//     LDS (row, chunk c) holds global chunk c ^ (row & 7); staging lane i
//     fetches global chunk (i&7)^((i>>3)&7); reads use (h*4+quad)^(l16&7).
//
//  prep_all: cast input -> cat[:, :1024]; cast memory -> memory_bf16;
//            copy memory -> out tail; transpose W_in1/W_mem1/W_in2/memory
//  G1: input_dot = relu(cat[:, :1024] @ W1T^T + b1)          (M=16384,N=1024,K=1024)
//  G2: memory_dot = relu(memory_bf16 @ WmT^T + bm)           (M=4096, N=1024,K=1024)
//  G3: att = input_dot @ memory_dot^T / 32   [batched z=8]   (M=2048, N=512, K=1024)
//  softmax rows (mask) fp32 att -> compact bf16 wAtt (=input_dot buffer)
//  G4: output_one = wAtt @ memT^T -> cat[:, 1024:2048]       (M=2048, N=1024,K=512)
//  G5: out = gate(cat @ W2T^T + b2)                          (M=16384,N=1024,K=2048)

using bf16_t = __hip_bfloat16;
typedef __attribute__((ext_vector_type(8))) __bf16 bf16x8;
typedef __attribute__((ext_vector_type(4))) float f32x4;

#define BM 128
#define BN 128
#define BK 64

#define EPI_RELU_BIAS_BF16 0
#define EPI_SCALE_F32      1
#define EPI_BF16           2
#define EPI_GATE_BIAS_F32  3

// direct global->LDS DMA, 16B per lane; LDS dest = wave-uniform base + lane*16
#define GLD16(gp, lp)                                                        \
    __builtin_amdgcn_global_load_lds(                                        \
        (const __attribute__((address_space(1))) void*)(gp),                 \
        (__attribute__((address_space(3))) void*)(lp), 16, 0, 0)

// C = A (M x K, row-major, LDA) @ B^T (B is N x K row-major, LDB), batched via blockIdx.z.
// Compile-time dims; XCD-aware column-major block remap (gridDim.y % 8 == 0).
template<int MODE, int K, int LDA, int LDB, int LDC>
__global__ __launch_bounds__(256)
void gemm_bt(const bf16_t* __restrict__ Ag, const bf16_t* __restrict__ Bg,
             void* __restrict__ Cg, const float* __restrict__ bias,
             long sA, long sB, long sC, float scale)
{
    __shared__ alignas(16) bf16_t As[BM * BK];   // 16 KB
    __shared__ alignas(16) bf16_t Bs[BN * BK];   // 16 KB

    const int z = blockIdx.z;
    const bf16_t* A = Ag + (long)z * sA;
    const bf16_t* B = Bg + (long)z * sB;

    const int tid  = threadIdx.x;
    const int lane = tid & 63;
    const int wave = tid >> 6;
    const int wr   = (wave >> 1) * 64;   // wave row offset in 128x128 tile
    const int wc   = (wave & 1) * 64;    // wave col offset
    const int quad = lane >> 4;          // 0..3
    const int l16  = lane & 15;

    // XCD swizzle: column-major reinterpretation of the linear block ID
    const int bidLin = blockIdx.y * gridDim.x + blockIdx.x;
    const int colBlk = bidLin / gridDim.y;
    const int rowBlk = bidLin - colBlk * gridDim.y;
    const int rowBase = rowBlk * BM;
    const int colBase = colBlk * BN;

    f32x4 acc[4][4];
    #pragma unroll
    for (int i = 0; i < 4; ++i)
        #pragma unroll
        for (int j = 0; j < 4; ++j)
            acc[i][j] = (f32x4){0.f, 0.f, 0.f, 0.f};

    // staging (global_load_lds, 16B/lane): wave w covers tile rows [w*32, w*32+32),
    // 4 rounds of 8 rows each for A and B. lane i -> row_local = i>>3,
    // LDS chunk = i&7; swizzle: fetch GLOBAL chunk (i&7) ^ (row_local&7).
    const int srow   = lane >> 3;                  // 0..7
    const int gchunk = (lane & 7) ^ srow;          // swizzled global chunk
    const int scol   = gchunk * 8;                 // element offset 0..56

    const bf16_t* pA = A + (long)(rowBase + wave * 32 + srow) * LDA + scol;
    const bf16_t* pB = B + (long)(colBase + wave * 32 + srow) * LDB + scol;
    bf16_t* lA = &As[(wave * 32) * BK];
    bf16_t* lB = &Bs[(wave * 32) * BK];

    // fragment-read chunk selectors (per-lane constants):
    // global chunk needed = h*4 + quad at row r; stored at LDS chunk (h*4+quad)^(r&7),
    // r&7 == l16&7 since wr/mi*16 are multiples of 16.
    const int csel0 = ((0 * 4 + quad) ^ (l16 & 7)) * 8;
    const int csel1 = ((1 * 4 + quad) ^ (l16 & 7)) * 8;

    #pragma unroll 1
    for (int k0 = 0; k0 < K; k0 += BK) {
        #pragma unroll
        for (int j = 0; j < 4; ++j) {
            GLD16(pA + (long)(j * 8) * LDA, lA + j * 8 * BK);
            GLD16(pB + (long)(j * 8) * LDB, lB + j * 8 * BK);
        }
        pA += BK; pB += BK;
        __syncthreads();   // drains vmcnt (global_load_lds)

        #pragma unroll
        for (int h = 0; h < 2; ++h) {
            const int cs = h ? csel1 : csel0;
            bf16x8 af[4], bfr[4];
            #pragma unroll
            for (int mi = 0; mi < 4; ++mi)
                af[mi] = *(const bf16x8*)(&As[(wr + mi * 16 + l16) * BK + cs]);
            #pragma unroll
            for (int ni = 0; ni < 4; ++ni)
                bfr[ni] = *(const bf16x8*)(&Bs[(wc + ni * 16 + l16) * BK + cs]);

            #pragma unroll
            for (int mi = 0; mi < 4; ++mi)
                #pragma unroll
                for (int ni = 0; ni < 4; ++ni)
                    acc[mi][ni] = __builtin_amdgcn_mfma_f32_16x16x32_bf16(
                        af[mi], bfr[ni], acc[mi][ni], 0, 0, 0);
        }
        __syncthreads();
    }

    // epilogue: C/D layout col = lane&15, row = quad*4 + reg
    #pragma unroll
    for (int mi = 0; mi < 4; ++mi) {
        #pragma unroll
        for (int ni = 0; ni < 4; ++ni) {
            #pragma unroll
            for (int r = 0; r < 4; ++r) {
                const int row = rowBase + wr + mi * 16 + quad * 4 + r;
                const int col = colBase + wc + ni * 16 + l16;
                const float v = acc[mi][ni][r];
                const long idx = (long)z * sC + (long)row * LDC + col;
                if (MODE == EPI_RELU_BIAS_BF16) {
                    float t = v + bias[col];
                    t = t > 0.f ? t : 0.f;
                    ((bf16_t*)Cg)[idx] = __float2bfloat16(t);
                } else if (MODE == EPI_SCALE_F32) {
                    ((float*)Cg)[idx] = v * scale;
                } else if (MODE == EPI_BF16) {
                    ((bf16_t*)Cg)[idx] = __float2bfloat16(v);
                } else { // EPI_GATE_BIAS_F32: sigmoid(p)*tanh(p) via one exp
                    float p = v + bias[col];
                    p = fminf(fmaxf(p, -30.f), 30.f);
                    const float u  = __expf(-p);
                    const float u2 = u * u;
                    ((float*)Cg)[idx] = (1.f - u2) / ((1.f + u) * (1.f + u2));
                }
            }
        }
    }
}

// fused prep: blocks [0,24576): cast input -> cat left half, cast memory -> memb,
//             copy memory -> out tail (float4 groups).
//             blocks [24576,32768): 32x32 transpose tiles for W1T/WmT/W2T/memT.
__global__ __launch_bounds__(256)
void prep_all(const float4* __restrict__ input, const float4* __restrict__ memory,
              const float* __restrict__ W_in1, const float* __restrict__ W_mem1,
              const float* __restrict__ W_in2,
              bf16_t* __restrict__ cat, bf16_t* __restrict__ memb,
              float4* __restrict__ outTail,
              bf16_t* __restrict__ W1T, bf16_t* __restrict__ WmT,
              bf16_t* __restrict__ W2T, bf16_t* __restrict__ memT)
{
    __shared__ float tile[32][33];
    const int bid = blockIdx.x;
    if (bid < 24576) {
        const long i = (long)bid * 256 + threadIdx.x;
        if (i < 4194304L) {               // input cast -> cat left half
            const float4 v = input[i];
            const long e = i << 2;
            const long row = e >> 10;
            const int  col = (int)(e & 1023);
            bf16_t* o = cat + row * 2048 + col;
            o[0] = __float2bfloat16(v.x);
            o[1] = __float2bfloat16(v.y);
            o[2] = __float2bfloat16(v.z);
            o[3] = __float2bfloat16(v.w);
        } else if (i < 5242880L) {        // memory cast (contiguous)
            const long j = i - 4194304L;
            const float4 v = memory[j];
            bf16_t* o = memb + (j << 2);
            o[0] = __float2bfloat16(v.x);
            o[1] = __float2bfloat16(v.y);
            o[2] = __float2bfloat16(v.z);
            o[3] = __float2bfloat16(v.w);
        } else {                          // memory passthrough -> out tail
            const long j = i - 5242880L;
            outTail[j] = memory[j];
        }
        return;
    }

    // transpose section: out[c][r] = bf16(in[r][c]), 32x32 tiles
    int local = bid - 24576;
    const float* in; bf16_t* out; int R, C, bx, by;
    if (local < 1024)      { in = W_in1;  out = W1T; R = 1024; C = 1024;
                             bx = local & 31; by = local >> 5; }
    else if (local < 2048) { local -= 1024; in = W_mem1; out = WmT; R = 1024; C = 1024;
                             bx = local & 31; by = local >> 5; }
    else if (local < 4096) { local -= 2048; in = W_in2;  out = W2T; R = 2048; C = 1024;
                             bx = local & 31; by = local >> 5; }
    else                   { local -= 4096;
                             const int zz = local >> 9;          // 0..7
                             const int r  = local & 511;
                             bx = r & 31; by = r >> 5;           // by 0..15
                             in  = (const float*)memory + (long)zz * 524288;
                             out = memT + (long)zz * 524288;
                             R = 512; C = 1024; }

    const int x = threadIdx.x & 31, y = threadIdx.x >> 5;   // y in 0..7
    const int c0 = bx * 32, r0 = by * 32;
    #pragma unroll
    for (int i = 0; i < 32; i += 8)
        tile[y + i][x] = in[(long)(r0 + y + i) * C + c0 + x];
    __syncthreads();
    #pragma unroll
    for (int i = 0; i < 32; i += 8)
        out[(long)(c0 + y + i) * R + r0 + x] = __float2bfloat16(tile[x][y + i]);
}

// one wave per row of 512; att fp32 in, compact bf16 weights out (row stride 512).
__global__ __launch_bounds__(256)
void softmax_rows(const float* __restrict__ att, const int* __restrict__ mask,
                  bf16_t* __restrict__ wAtt)
{
    const int lane = threadIdx.x & 63;
    const long row = (long)blockIdx.x * 4 + (threadIdx.x >> 6);
    const int n = (int)(row >> 11);          // 2048 rows per batch
    const float* base = att + row * 512;
    const int* mrow = mask + n * 512;

    float v[8];
    #pragma unroll
    for (int j = 0; j < 8; ++j) {
        const int idx = j * 64 + lane;
        const float x = base[idx];
        v[j] = mrow[idx] ? x : -1e30f;
    }
    float mx = v[0];
    #pragma unroll
    for (int j = 1; j < 8; ++j) mx = fmaxf(mx, v[j]);
    #pragma unroll
    for (int off = 32; off >= 1; off >>= 1) mx = fmaxf(mx, __shfl_xor(mx, off, 64));
    float s = 0.f;
    #pragma unroll
    for (int j = 0; j < 8; ++j) { v[j] = __expf(v[j] - mx); s += v[j]; }
    #pragma unroll
    for (int off = 32; off >= 1; off >>= 1) s += __shfl_xor(s, off, 64);
    const float inv = 1.0f / s;

    bf16_t* w = wAtt + row * 512;
    #pragma unroll
    for (int j = 0; j < 8; ++j)
        w[j * 64 + lane] = __float2bfloat16(v[j] * inv);
}

extern "C" void kernel_launch(void* const* d_in, const int* in_sizes, int n_in,
                              void* d_out, int out_size, void* d_ws, size_t ws_size,
                              hipStream_t stream)
{
    const float* input  = (const float*)d_in[0];   // 8 x 2048 x 1024
    const float* memory = (const float*)d_in[1];   // 8 x 512 x 1024
    const int*   mask   = (const int*)  d_in[2];   // 8 x 512
    const float* W_in1  = (const float*)d_in[3];   // 1024 x 1024
    const float* b_in1  = (const float*)d_in[4];
    const float* W_mem1 = (const float*)d_in[5];   // 1024 x 1024
    const float* b_mem1 = (const float*)d_in[6];
    const float* W_in2  = (const float*)d_in[7];   // 2048 x 1024
    const float* b_in2  = (const float*)d_in[8];
    float* out = (float*)d_out;                    // 16777216 gated + 4194304 memory

    char* ws = (char*)d_ws;
    bf16_t* cat         = (bf16_t*)(ws);                 // 16384 x 2048   (67108864 B)
    bf16_t* input_dot   = (bf16_t*)(ws + 67108864);      // 16384 x 1024   (33554432 B)
    bf16_t* memory_dot  = (bf16_t*)(ws + 100663296);     //  4096 x 1024   ( 8388608 B)
    bf16_t* memory_bf16 = (bf16_t*)(ws + 109051904);     //  4096 x 1024   ( 8388608 B)
    bf16_t* memT        = (bf16_t*)(ws + 117440512);     // 8 x 1024 x 512 ( 8388608 B)
    bf16_t* W1T         = (bf16_t*)(ws + 125829120);     // 1024 x 1024    ( 2097152 B)
    bf16_t* WmT         = (bf16_t*)(ws + 127926272);     // 1024 x 1024    ( 2097152 B)
    bf16_t* W2T         = (bf16_t*)(ws + 130023424);     // 1024 x 2048    ( 4194304 B)
    float*  att         = (float*)(ws + 134217728);      // 8 x 2048 x 512 (33554432 B) -> end 167772160
    bf16_t* wAtt        = input_dot;   // reclaimed after G3: compact bf16 softmax weights

    // fused prep (casts + passthrough + all transposes)
    prep_all<<<32768, 256, 0, stream>>>((const float4*)input, (const float4*)memory,
                                        W_in1, W_mem1, W_in2,
                                        cat, memory_bf16, (float4*)(out + 16777216L),
                                        W1T, WmT, W2T, memT);

    // G1: input_dot = relu(input @ W_in1 + b_in1)
    gemm_bt<EPI_RELU_BIAS_BF16, 1024, 2048, 1024, 1024><<<dim3(8, 128, 1), 256, 0, stream>>>(
        cat, W1T, input_dot, b_in1, 0, 0, 0, 1.0f);
    // G2: memory_dot = relu(memory @ W_mem1 + b_mem1)
    gemm_bt<EPI_RELU_BIAS_BF16, 1024, 1024, 1024, 1024><<<dim3(8, 32, 1), 256, 0, stream>>>(
        memory_bf16, WmT, memory_dot, b_mem1, 0, 0, 0, 1.0f);
    // G3: att = input_dot @ memory_dot^T / 32   (batched)
    gemm_bt<EPI_SCALE_F32, 1024, 1024, 1024, 512><<<dim3(4, 16, 8), 256, 0, stream>>>(
        input_dot, memory_dot, att, nullptr,
        2048L * 1024, 512L * 1024, 2048L * 512, 0.03125f);
    // softmax: fp32 att -> compact bf16 wAtt (input_dot buffer is dead after G3)
    softmax_rows<<<4096, 256, 0, stream>>>(att, mask, wAtt);
    // G4: output_one = wAtt @ memT^T -> cat[:, 1024:2048]   (batched, dense A)
    gemm_bt<EPI_BF16, 512, 512, 512, 2048><<<dim3(8, 16, 8), 256, 0, stream>>>(
        wAtt, memT, cat + 1024, nullptr,
        2048L * 512, 1024L * 512, 2048L * 2048, 1.0f);
    // G5: out = sigmoid(pre) * tanh(pre), pre = cat @ W_in2 + b_in2
    gemm_bt<EPI_GATE_BIAS_F32, 2048, 2048, 2048, 1024><<<dim3(8, 128, 1), 256, 0, stream>>>(
        cat, W2T, out, b_in2, 0, 0, 0, 1.0f);
}